// Round 2
// baseline (180.132 us; speedup 1.0000x reference)
//
#include <hip/hip_runtime.h>
#include <hip/hip_bf16.h>

#define NLEAF 256
#define MBLK 256
#define THREADS 512

typedef __attribute__((ext_vector_type(4))) float f32x4;
typedef __attribute__((ext_vector_type(4))) unsigned int uint4v;
typedef __attribute__((ext_vector_type(8))) __bf16 bf16x8;
typedef __attribute__((ext_vector_type(4))) __bf16 bf16x4;

// LDS layout (bytes)
#define OFF_DIST 0        // 131072: dist bf16 [256 leaves][256 rows]
#define OFF_XP   131072   // 16384 : x-stage f32 chunk / P-level ping-pong
#define OFF_T    147456   // 4096  : T leaf tile (bf16, swizzled)
#define OFF_AC   151552   // 1024  : A_c[255] f32
#define OFF_BC   152576   // 1024  : B_c[255] f32
#define OFF_ANG  153600   // 1024  : angles[256] f32
#define OFF_RAY  154624   // 256   : ray[64] f32
#define SMEM_BYTES 154880

__device__ __forceinline__ float sigf(float s) { return 1.0f / (1.0f + __expf(-s)); }

// Pre-pass: T fp32 [l][k(64)][w(32)] -> bf16 workspace, per-leaf layout [w][k]
// with XOR swizzle baked in so a LINEAR LDS copy lands bank-conflict-free data.
__global__ void prep_T(const float* __restrict__ T, __bf16* __restrict__ wsT) {
  int gid = blockIdx.x * 256 + threadIdx.x;      // 524288 total
  int l = gid >> 11;
  int rem = gid & 2047;
  int k = rem >> 5;
  int w = rem & 31;
  float v = T[gid];
  int off = (w * 128 + 2 * k) ^ ((w & 7) << 4);  // byte offset within 4KB tile
  wsT[((size_t)l * 4096 + off) >> 1] = (__bf16)v;
}

template <bool USE_WS>
__global__ __launch_bounds__(THREADS, 2)
void prl_main(const float* __restrict__ x, const float* __restrict__ ray,
              const float* __restrict__ w_i, const float* __restrict__ b_i,
              const float* __restrict__ a_i, const void* __restrict__ tsrc,
              float* __restrict__ out) {
  extern __shared__ char smem[];
  const int tid = threadIdx.x;
  const int lane = tid & 63;
  const int wid = tid >> 6;
  const int g = lane >> 4;
  const int ln = lane & 15;
  const int row0 = blockIdx.x * MBLK;

  float* A_c = (float*)(smem + OFF_AC);
  float* B_c = (float*)(smem + OFF_BC);
  float* angles = (float*)(smem + OFF_ANG);
  float* ray_l = (float*)(smem + OFF_RAY);
  __bf16* distb = (__bf16*)(smem + OFF_DIST);

  // ---- stage node constants + ray ----
  if (tid < 255) {
    float aa = 1.0f + a_i[tid];
    A_c[tid] = (0.5f + sigf(w_i[tid])) * aa;
    B_c[tid] = -sigf(b_i[tid]) * aa;
  }
  if (tid >= 256 && tid < 320) ray_l[tid - 256] = ray[tid - 256];
  __syncthreads();

  // ---- x staging (4 chunks of 64 rows), angle computation, A-fragment extraction ----
  bf16x8 afrag[2][2] = {};
  float* xp = (float*)(smem + OFF_XP);
  for (int c = 0; c < 4; ++c) {
    const float* xg = x + (size_t)(row0 + c * 64) * 64;
#pragma unroll
    for (int p = 0; p < 2; ++p) {
      int idx = p * 512 + tid;  // float4 slot 0..1023 in chunk
      f32x4 v = *(const f32x4*)(xg + idx * 4);
      *(f32x4*)(xp + idx * 4) = v;
      int cg = idx & 15;
      f32x4 rv = *(const f32x4*)(ray_l + cg * 4);
      float a0 = v[0] * v[0] + v[1] * v[1] + v[2] * v[2] + v[3] * v[3];
      float a1 = v[0] * rv[0] + v[1] * rv[1] + v[2] * rv[2] + v[3] * rv[3];
      float a2 = rv[0] * rv[0] + rv[1] * rv[1] + rv[2] * rv[2] + rv[3] * rv[3];
#pragma unroll
      for (int s = 1; s < 16; s <<= 1) {
        a0 += __shfl_xor(a0, s, 64);
        a1 += __shfl_xor(a1, s, 64);
        a2 += __shfl_xor(a2, s, 64);
      }
      if ((tid & 15) == 0) {
        int r = idx >> 4;  // local row 0..63
        float xn = fmaxf(sqrtf(a0), 1e-8f);
        float rn = fmaxf(sqrtf(a2), 1e-8f);
        float cs = a1 / (xn * rn);
        cs = fminf(fmaxf(cs, -1.0f), 1.0f);
        angles[c * 64 + r] = acosf(cs) * 0.31830988618379067f;
      }
    }
    __syncthreads();
    if ((wid >> 1) == c) {  // waves 2c, 2c+1 own rows of this chunk
#pragma unroll
      for (int mt = 0; mt < 2; ++mt)
#pragma unroll
        for (int kt = 0; kt < 2; ++kt) {
          int rl = (wid & 1) * 32 + mt * 16 + ln;
          int k0 = kt * 32 + g * 8;
          f32x4 u0 = *(const f32x4*)(xp + rl * 64 + k0);
          f32x4 u1 = *(const f32x4*)(xp + rl * 64 + k0 + 4);
          bf16x8 af;
          af[0] = (__bf16)u0[0]; af[1] = (__bf16)u0[1];
          af[2] = (__bf16)u0[2]; af[3] = (__bf16)u0[3];
          af[4] = (__bf16)u1[0]; af[5] = (__bf16)u1[1];
          af[6] = (__bf16)u1[2]; af[7] = (__bf16)u1[3];
          afrag[mt][kt] = af;
        }
    }
    __syncthreads();
  }

  // ---- tree probabilities: level passes, bf16, ping-pong in dead x region ----
  __bf16* PA = (__bf16*)(smem + OFF_XP);
  __bf16* PB = (__bf16*)(smem + OFF_XP + 8192);
  // level 0 -> P1 (512 entries) in PA
  if (tid < 256) {
    float ang = angles[tid];
    float d = sigf(fmaf(A_c[0], ang, B_c[0]));
    PA[tid] = (__bf16)d;
    PA[256 + tid] = (__bf16)(1.0f - d);
  }
  __syncthreads();
  // P1(PA) -> P2(PB, 1024)
  {
    int n = tid >> 8, r = tid & 255;
    float p = (float)PA[tid];
    float ang = angles[r];
    float d = sigf(fmaf(A_c[1 + n], ang, B_c[1 + n]));
    PB[(2 * n) * 256 + r] = (__bf16)(p * d);
    PB[(2 * n + 1) * 256 + r] = (__bf16)(p * (1.0f - d));
  }
  __syncthreads();
  // P2(PB) -> P3(PA, 2048)
#pragma unroll
  for (int it = 0; it < 2; ++it) {
    int e = it * 512 + tid;
    int n = e >> 8, r = e & 255;
    float p = (float)PB[e];
    float ang = angles[r];
    float d = sigf(fmaf(A_c[3 + n], ang, B_c[3 + n]));
    PA[(2 * n) * 256 + r] = (__bf16)(p * d);
    PA[(2 * n + 1) * 256 + r] = (__bf16)(p * (1.0f - d));
  }
  __syncthreads();
  // P3(PA) -> P4(PB, 4096)
#pragma unroll
  for (int it = 0; it < 4; ++it) {
    int e = it * 512 + tid;
    int n = e >> 8, r = e & 255;
    float p = (float)PA[e];
    float ang = angles[r];
    float d = sigf(fmaf(A_c[7 + n], ang, B_c[7 + n]));
    PB[(2 * n) * 256 + r] = (__bf16)(p * d);
    PB[(2 * n + 1) * 256 + r] = (__bf16)(p * (1.0f - d));
  }
  __syncthreads();
  // P4(PB) -> fused levels 4..7 -> dist [leaf][row]
#pragma unroll
  for (int it = 0; it < 8; ++it) {
    int e = it * 512 + tid;
    int n4 = e >> 8, r = e & 255;
    float p4 = (float)PB[e];
    float ang = angles[r];
    float d4 = sigf(fmaf(A_c[15 + n4], ang, B_c[15 + n4]));
    float p5[2] = {p4 * d4, p4 * (1.0f - d4)};
#pragma unroll
    for (int b5 = 0; b5 < 2; ++b5) {
      int n5 = 2 * n4 + b5;
      float d5 = sigf(fmaf(A_c[31 + n5], ang, B_c[31 + n5]));
      float p6[2] = {p5[b5] * d5, p5[b5] * (1.0f - d5)};
#pragma unroll
      for (int b6 = 0; b6 < 2; ++b6) {
        int n6 = 2 * n5 + b6;
        float d6 = sigf(fmaf(A_c[63 + n6], ang, B_c[63 + n6]));
        float p7[2] = {p6[b6] * d6, p6[b6] * (1.0f - d6)};
#pragma unroll
        for (int b7 = 0; b7 < 2; ++b7) {
          int n7 = 2 * n6 + b7;
          float d7 = sigf(fmaf(A_c[127 + n7], ang, B_c[127 + n7]));
          float pv = p7[b7];
          distb[(2 * n7) * 256 + r] = (__bf16)(pv * d7);
          distb[(2 * n7 + 1) * 256 + r] = (__bf16)(pv * (1.0f - d7));
        }
      }
    }
  }

  // ---- leaf loop: reg-staged T tile -> LDS, MFMA, dist-scaled accumulate ----
  f32x4 acc[2][2] = {};
  const int strip = wid * 32;
  char* tb = smem + OFF_T;

  uint4v tv = {};
  f32x4 tvf = {};
  if constexpr (USE_WS) {
    if (tid < 256) tv = *(const uint4v*)((const char*)tsrc + tid * 16);
  } else {
    tvf = *(const f32x4*)((const float*)tsrc + tid * 4);
  }

  for (int l = 0; l < NLEAF; ++l) {
    __syncthreads();  // everyone done with previous tile; reg loads arrived
    if constexpr (USE_WS) {
      if (tid < 256) *(uint4v*)(tb + tid * 16) = tv;
    } else {
      int e4 = tid * 4, k = e4 >> 5, wb = e4 & 31;
#pragma unroll
      for (int j = 0; j < 4; ++j) {
        int w = wb + j;
        int ad = (w * 128 + 2 * k) ^ ((w & 7) << 4);
        *(__bf16*)(tb + ad) = (__bf16)tvf[j];
      }
    }
    __syncthreads();  // tile l visible
    if (l + 1 < NLEAF) {
      if constexpr (USE_WS) {
        if (tid < 256)
          tv = *(const uint4v*)((const char*)tsrc + (size_t)(l + 1) * 4096 + tid * 16);
      } else {
        tvf = *(const f32x4*)((const float*)tsrc + (size_t)(l + 1) * 2048 + tid * 4);
      }
    }
    // B fragments (swizzled reads)
    bf16x8 bf[2][2];
#pragma unroll
    for (int kt = 0; kt < 2; ++kt)
#pragma unroll
      for (int nt = 0; nt < 2; ++nt) {
        int w = nt * 16 + ln;
        int ad = (w * 128 + kt * 64 + g * 16) ^ ((w & 7) << 4);
        bf[kt][nt] = *(const bf16x8*)(tb + ad);
      }
    // dist for this wave's rows (4 consecutive rows per m-tile)
    f32x4 dv[2];
#pragma unroll
    for (int mt = 0; mt < 2; ++mt) {
      int row = strip + mt * 16 + g * 4;
      bf16x4 dd = *(const bf16x4*)(distb + l * 256 + row);
      dv[mt] = (f32x4){(float)dd[0], (float)dd[1], (float)dd[2], (float)dd[3]};
    }
    f32x4 zero = {0.0f, 0.0f, 0.0f, 0.0f};
#pragma unroll
    for (int mt = 0; mt < 2; ++mt)
#pragma unroll
      for (int nt = 0; nt < 2; ++nt) {
        f32x4 y = __builtin_amdgcn_mfma_f32_16x16x32_bf16(afrag[mt][0], bf[0][nt], zero, 0, 0, 0);
        y = __builtin_amdgcn_mfma_f32_16x16x32_bf16(afrag[mt][1], bf[1][nt], y, 0, 0, 0);
        acc[mt][nt] += dv[mt] * y;
      }
  }

  // ---- epilogue: C/D layout col=lane&15, row=(lane>>4)*4+reg ----
#pragma unroll
  for (int mt = 0; mt < 2; ++mt)
#pragma unroll
    for (int nt = 0; nt < 2; ++nt)
#pragma unroll
      for (int e = 0; e < 4; ++e) {
        int row = row0 + strip + mt * 16 + g * 4 + e;
        out[(size_t)row * 32 + nt * 16 + ln] = acc[mt][nt][e];
      }
}

extern "C" void kernel_launch(void* const* d_in, const int* in_sizes, int n_in,
                              void* d_out, int out_size, void* d_ws, size_t ws_size,
                              hipStream_t stream) {
  const float* x = (const float*)d_in[0];
  const float* ray = (const float*)d_in[1];
  const float* T = (const float*)d_in[2];
  const float* w_i = (const float*)d_in[3];
  const float* b_i = (const float*)d_in[4];
  const float* a_i = (const float*)d_in[5];
  float* out = (float*)d_out;

  bool use_ws = ws_size >= (size_t)NLEAF * 4096;
  if (use_ws) {
    hipFuncSetAttribute(reinterpret_cast<const void*>(&prl_main<true>),
                        hipFuncAttributeMaxDynamicSharedMemorySize, SMEM_BYTES);
    prep_T<<<2048, 256, 0, stream>>>(T, (__bf16*)d_ws);
    prl_main<true><<<256, THREADS, SMEM_BYTES, stream>>>(x, ray, w_i, b_i, a_i, d_ws, out);
  } else {
    hipFuncSetAttribute(reinterpret_cast<const void*>(&prl_main<false>),
                        hipFuncAttributeMaxDynamicSharedMemorySize, SMEM_BYTES);
    prl_main<false><<<256, THREADS, SMEM_BYTES, stream>>>(x, ray, w_i, b_i, a_i, T, out);
  }
}

// Round 4
// 163.795 us; speedup vs baseline: 1.0997x; 1.0997x over previous
//
#include <hip/hip_runtime.h>
#include <hip/hip_bf16.h>

#define NLEAF 256
#define MBLK 256
#define THREADS 512

typedef __attribute__((ext_vector_type(4))) float f32x4;
typedef __attribute__((ext_vector_type(4))) unsigned int uint4v;
typedef __attribute__((ext_vector_type(8))) __bf16 bf16x8;
typedef __attribute__((ext_vector_type(4))) __bf16 bf16x4;

// LDS layout (bytes)
#define OFF_DIST 0        // 131072: dist bf16 [256 leaves][256 rows]
#define OFF_XP   131072   // 16384 : x-stage f32 chunk / P-level ping-pong
#define OFF_T    147456   // 8192  : T leaf tile DOUBLE buffer (bf16, swizzled)
#define OFF_AC   155648   // 1024  : A_c[255] f32
#define OFF_BC   156672   // 1024  : B_c[255] f32
#define OFF_ANG  157696   // 1024  : angles[256] f32
#define OFF_RAY  158720   // 256   : ray[64] f32
#define SMEM_BYTES 158976

__device__ __forceinline__ float sigf(float s) { return 1.0f / (1.0f + __expf(-s)); }

// Pre-pass: T fp32 [l][k(64)][w(32)] -> bf16 ws, per-leaf [w][k] swizzled.
// LDS-transpose so global reads AND writes are fully coalesced.
__global__ __launch_bounds__(256) void prep_T(const float* __restrict__ T,
                                              __bf16* __restrict__ wsT) {
  __shared__ char tile[4096];
  const int l = blockIdx.x;
  const float* src = T + (size_t)l * 2048;
  const int t = threadIdx.x;
#pragma unroll
  for (int p = 0; p < 2; ++p) {
    int e = p * 1024 + t * 4;  // element within leaf: k = e>>5, w = e&31
    f32x4 v = *(const f32x4*)(src + e);
    int k = e >> 5, w0 = e & 31;
#pragma unroll
    for (int j = 0; j < 4; ++j) {
      int w = w0 + j;
      int off = (w * 128 + 2 * k) ^ ((w & 7) << 4);
      *(__bf16*)(tile + off) = (__bf16)v[j];
    }
  }
  __syncthreads();
  *(uint4v*)((char*)wsT + (size_t)l * 4096 + t * 16) = *(const uint4v*)(tile + t * 16);
}

template <bool USE_WS>
__global__ __launch_bounds__(THREADS, 2)
void prl_main(const float* __restrict__ x, const float* __restrict__ ray,
              const float* __restrict__ w_i, const float* __restrict__ b_i,
              const float* __restrict__ a_i, const void* __restrict__ tsrc,
              float* __restrict__ out) {
  extern __shared__ char smem[];
  const int tid = threadIdx.x;
  const int lane = tid & 63;
  const int wid = tid >> 6;
  const int g = lane >> 4;
  const int ln = lane & 15;
  const int row0 = blockIdx.x * MBLK;

  float* A_c = (float*)(smem + OFF_AC);
  float* B_c = (float*)(smem + OFF_BC);
  float* angles = (float*)(smem + OFF_ANG);
  float* ray_l = (float*)(smem + OFF_RAY);
  __bf16* distb = (__bf16*)(smem + OFF_DIST);

  // ---- stage node constants + ray ----
  if (tid < 255) {
    float aa = 1.0f + a_i[tid];
    A_c[tid] = (0.5f + sigf(w_i[tid])) * aa;
    B_c[tid] = -sigf(b_i[tid]) * aa;
  }
  if (tid >= 256 && tid < 320) ray_l[tid - 256] = ray[tid - 256];
  __syncthreads();

  // ---- x staging (4 chunks of 64 rows), angles, A-fragment extraction ----
  bf16x8 afrag[2][2] = {};
  float* xp = (float*)(smem + OFF_XP);
  for (int c = 0; c < 4; ++c) {
    const float* xg = x + (size_t)(row0 + c * 64) * 64;
#pragma unroll
    for (int p = 0; p < 2; ++p) {
      int idx = p * 512 + tid;  // float4 slot 0..1023 in chunk
      f32x4 v = *(const f32x4*)(xg + idx * 4);
      *(f32x4*)(xp + idx * 4) = v;
      int cg = idx & 15;
      f32x4 rv = *(const f32x4*)(ray_l + cg * 4);
      float a0 = v[0] * v[0] + v[1] * v[1] + v[2] * v[2] + v[3] * v[3];
      float a1 = v[0] * rv[0] + v[1] * rv[1] + v[2] * rv[2] + v[3] * rv[3];
      float a2 = rv[0] * rv[0] + rv[1] * rv[1] + rv[2] * rv[2] + rv[3] * rv[3];
#pragma unroll
      for (int s = 1; s < 16; s <<= 1) {
        a0 += __shfl_xor(a0, s, 64);
        a1 += __shfl_xor(a1, s, 64);
        a2 += __shfl_xor(a2, s, 64);
      }
      if ((tid & 15) == 0) {
        int r = idx >> 4;
        float xn = fmaxf(sqrtf(a0), 1e-8f);
        float rn = fmaxf(sqrtf(a2), 1e-8f);
        float cs = a1 / (xn * rn);
        cs = fminf(fmaxf(cs, -1.0f), 1.0f);
        angles[c * 64 + r] = acosf(cs) * 0.31830988618379067f;
      }
    }
    __syncthreads();
    if ((wid >> 1) == c) {
#pragma unroll
      for (int mt = 0; mt < 2; ++mt)
#pragma unroll
        for (int kt = 0; kt < 2; ++kt) {
          int rl = (wid & 1) * 32 + mt * 16 + ln;
          int k0 = kt * 32 + g * 8;
          f32x4 u0 = *(const f32x4*)(xp + rl * 64 + k0);
          f32x4 u1 = *(const f32x4*)(xp + rl * 64 + k0 + 4);
          bf16x8 af;
          af[0] = (__bf16)u0[0]; af[1] = (__bf16)u0[1];
          af[2] = (__bf16)u0[2]; af[3] = (__bf16)u0[3];
          af[4] = (__bf16)u1[0]; af[5] = (__bf16)u1[1];
          af[6] = (__bf16)u1[2]; af[7] = (__bf16)u1[3];
          afrag[mt][kt] = af;
        }
    }
    __syncthreads();
  }

  // ---- tree probabilities (level passes, bf16, ping-pong in dead x region) ----
  __bf16* PA = (__bf16*)(smem + OFF_XP);
  __bf16* PB = (__bf16*)(smem + OFF_XP + 8192);
  if (tid < 256) {
    float ang = angles[tid];
    float d = sigf(fmaf(A_c[0], ang, B_c[0]));
    PA[tid] = (__bf16)d;
    PA[256 + tid] = (__bf16)(1.0f - d);
  }
  __syncthreads();
  {
    int n = tid >> 8, r = tid & 255;
    float p = (float)PA[tid];
    float ang = angles[r];
    float d = sigf(fmaf(A_c[1 + n], ang, B_c[1 + n]));
    PB[(2 * n) * 256 + r] = (__bf16)(p * d);
    PB[(2 * n + 1) * 256 + r] = (__bf16)(p * (1.0f - d));
  }
  __syncthreads();
#pragma unroll
  for (int it = 0; it < 2; ++it) {
    int e = it * 512 + tid;
    int n = e >> 8, r = e & 255;
    float p = (float)PB[e];
    float ang = angles[r];
    float d = sigf(fmaf(A_c[3 + n], ang, B_c[3 + n]));
    PA[(2 * n) * 256 + r] = (__bf16)(p * d);
    PA[(2 * n + 1) * 256 + r] = (__bf16)(p * (1.0f - d));
  }
  __syncthreads();
#pragma unroll
  for (int it = 0; it < 4; ++it) {
    int e = it * 512 + tid;
    int n = e >> 8, r = e & 255;
    float p = (float)PA[e];
    float ang = angles[r];
    float d = sigf(fmaf(A_c[7 + n], ang, B_c[7 + n]));
    PB[(2 * n) * 256 + r] = (__bf16)(p * d);
    PB[(2 * n + 1) * 256 + r] = (__bf16)(p * (1.0f - d));
  }
  __syncthreads();
#pragma unroll
  for (int it = 0; it < 8; ++it) {
    int e = it * 512 + tid;
    int n4 = e >> 8, r = e & 255;
    float p4 = (float)PB[e];
    float ang = angles[r];
    float d4 = sigf(fmaf(A_c[15 + n4], ang, B_c[15 + n4]));
    float p5[2] = {p4 * d4, p4 * (1.0f - d4)};
#pragma unroll
    for (int b5 = 0; b5 < 2; ++b5) {
      int n5 = 2 * n4 + b5;
      float d5 = sigf(fmaf(A_c[31 + n5], ang, B_c[31 + n5]));
      float p6[2] = {p5[b5] * d5, p5[b5] * (1.0f - d5)};
#pragma unroll
      for (int b6 = 0; b6 < 2; ++b6) {
        int n6 = 2 * n5 + b6;
        float d6 = sigf(fmaf(A_c[63 + n6], ang, B_c[63 + n6]));
        float p7[2] = {p6[b6] * d6, p6[b6] * (1.0f - d6)};
#pragma unroll
        for (int b7 = 0; b7 < 2; ++b7) {
          int n7 = 2 * n6 + b7;
          float d7 = sigf(fmaf(A_c[127 + n7], ang, B_c[127 + n7]));
          float pv = p7[b7];
          distb[(2 * n7) * 256 + r] = (__bf16)(pv * d7);
          distb[(2 * n7 + 1) * 256 + r] = (__bf16)(pv * (1.0f - d7));
        }
      }
    }
  }

  // ---- leaf loop: double-buffered T tile, ONE barrier per iteration ----
  // iter l: write tile l+1 -> buf[(l+1)&1]  (regs, loaded iter l-1)
  //         issue load tile l+2
  //         read frags from buf[l&1], MFMA, scale-accumulate
  //         barrier   (protects buf[l&1] from iter l+1's writes)
  f32x4 acc[2][2] = {};
  const int strip = wid * 32;
  char* tb = smem + OFF_T;

  uint4v tv = {};
  f32x4 tvf = {};
  if constexpr (USE_WS) {
    if (tid < 256) {
      tv = *(const uint4v*)((const char*)tsrc + tid * 16);
      *(uint4v*)(tb + tid * 16) = tv;  // tile 0 -> buf0
      tv = *(const uint4v*)((const char*)tsrc + 4096 + tid * 16);  // tile 1
    }
  } else {
    tvf = *(const f32x4*)((const float*)tsrc + tid * 4);
    {
      int e4 = tid * 4, k = e4 >> 5, wb = e4 & 31;
#pragma unroll
      for (int j = 0; j < 4; ++j) {
        int w = wb + j;
        int ad = (w * 128 + 2 * k) ^ ((w & 7) << 4);
        *(__bf16*)(tb + ad) = (__bf16)tvf[j];
      }
    }
    tvf = *(const f32x4*)((const float*)tsrc + 2048 + tid * 4);
  }
  __syncthreads();  // tile 0 visible

  for (int l = 0; l < NLEAF; ++l) {
    char* cur = tb + (l & 1) * 4096;
    char* nxt = tb + ((l + 1) & 1) * 4096;
    if constexpr (USE_WS) {
      if (tid < 256) {
        if (l + 1 < NLEAF) *(uint4v*)(nxt + tid * 16) = tv;
        if (l + 2 < NLEAF)
          tv = *(const uint4v*)((const char*)tsrc + (size_t)(l + 2) * 4096 + tid * 16);
      }
    } else {
      if (l + 1 < NLEAF) {
        int e4 = tid * 4, k = e4 >> 5, wb = e4 & 31;
#pragma unroll
        for (int j = 0; j < 4; ++j) {
          int w = wb + j;
          int ad = (w * 128 + 2 * k) ^ ((w & 7) << 4);
          *(__bf16*)(nxt + ad) = (__bf16)tvf[j];
        }
      }
      if (l + 2 < NLEAF)
        tvf = *(const f32x4*)((const float*)tsrc + (size_t)(l + 2) * 2048 + tid * 4);
    }
    // dist for this wave's rows (4 consecutive rows per m-tile)
    f32x4 dv[2];
#pragma unroll
    for (int mt = 0; mt < 2; ++mt) {
      int row = strip + mt * 16 + g * 4;
      bf16x4 dd = *(const bf16x4*)(distb + l * 256 + row);
      dv[mt] = (f32x4){(float)dd[0], (float)dd[1], (float)dd[2], (float)dd[3]};
    }
    // B fragments (swizzled reads)
    bf16x8 bfr[2][2];
#pragma unroll
    for (int kt = 0; kt < 2; ++kt)
#pragma unroll
      for (int nt = 0; nt < 2; ++nt) {
        int w = nt * 16 + ln;
        int ad = (w * 128 + kt * 64 + g * 16) ^ ((w & 7) << 4);
        bfr[kt][nt] = *(const bf16x8*)(cur + ad);
      }
    f32x4 zero = {0.0f, 0.0f, 0.0f, 0.0f};
#pragma unroll
    for (int mt = 0; mt < 2; ++mt)
#pragma unroll
      for (int nt = 0; nt < 2; ++nt) {
        f32x4 y = __builtin_amdgcn_mfma_f32_16x16x32_bf16(afrag[mt][0], bfr[0][nt], zero, 0, 0, 0);
        y = __builtin_amdgcn_mfma_f32_16x16x32_bf16(afrag[mt][1], bfr[1][nt], y, 0, 0, 0);
        acc[mt][nt] += dv[mt] * y;
      }
    __syncthreads();
  }

  // ---- epilogue: C/D layout col=lane&15, row=(lane>>4)*4+reg ----
#pragma unroll
  for (int mt = 0; mt < 2; ++mt)
#pragma unroll
    for (int nt = 0; nt < 2; ++nt)
#pragma unroll
      for (int e = 0; e < 4; ++e) {
        int row = row0 + strip + mt * 16 + g * 4 + e;
        out[(size_t)row * 32 + nt * 16 + ln] = acc[mt][nt][e];
      }
}

extern "C" void kernel_launch(void* const* d_in, const int* in_sizes, int n_in,
                              void* d_out, int out_size, void* d_ws, size_t ws_size,
                              hipStream_t stream) {
  const float* x = (const float*)d_in[0];
  const float* ray = (const float*)d_in[1];
  const float* T = (const float*)d_in[2];
  const float* w_i = (const float*)d_in[3];
  const float* b_i = (const float*)d_in[4];
  const float* a_i = (const float*)d_in[5];
  float* out = (float*)d_out;

  bool use_ws = ws_size >= (size_t)NLEAF * 4096;
  if (use_ws) {
    hipFuncSetAttribute(reinterpret_cast<const void*>(&prl_main<true>),
                        hipFuncAttributeMaxDynamicSharedMemorySize, SMEM_BYTES);
    prep_T<<<256, 256, 0, stream>>>(T, (__bf16*)d_ws);
    prl_main<true><<<256, THREADS, SMEM_BYTES, stream>>>(x, ray, w_i, b_i, a_i, d_ws, out);
  } else {
    hipFuncSetAttribute(reinterpret_cast<const void*>(&prl_main<false>),
                        hipFuncAttributeMaxDynamicSharedMemorySize, SMEM_BYTES);
    prl_main<false><<<256, THREADS, SMEM_BYTES, stream>>>(x, ray, w_i, b_i, a_i, T, out);
  }
}